// Round 1
// 926.130 us; speedup vs baseline: 1.0607x; 1.0607x over previous
//
#include <hip/hip_runtime.h>
#include <hip/hip_bf16.h>
#include <hip/hip_fp16.h>
#include <stdint.h>

// N=1024 queries, R=100000 refs, H=512, O=256, K=1000.
#define NQ 1024
#define NR 100000
#define NH 512
#define NO 256
#define NK 1000
#define NBINS 4096           // sim in [-1,1): bin width 4.883e-4
#define DEF_CAP 1024
#define CND_CAP 768
#define DELTA 2.0e-3f        // covers bf16-GEMM sim error + fp16 store quant

typedef __attribute__((ext_vector_type(8))) short bf16x8;
typedef __attribute__((ext_vector_type(4))) float f32x4;
typedef __attribute__((address_space(3))) void lds_void;
typedef const __attribute__((address_space(1))) void glb_void;

// pack two fp32 into two bf16 (truncation) with one v_perm_b32
static __device__ inline uint32_t pack_bf16_trunc(float lo, float hi) {
    return __builtin_amdgcn_perm(__float_as_uint(hi), __float_as_uint(lo), 0x07060302u);
}

// ---------------------------------------------------------------------------
// K0: fp32 -> bf16 conversion + fp64 inverse L2 norm. One wave per row.
// ---------------------------------------------------------------------------
__global__ __launch_bounds__(256) void conv_norm_kernel(const float* __restrict__ src,
                                                        int rows,
                                                        ushort* __restrict__ dst_bf,
                                                        double* __restrict__ inv_out)
{
    const int wave = threadIdx.x >> 6;
    const int lane = threadIdx.x & 63;
    const int row  = blockIdx.x * 4 + wave;
    if (row >= rows) return;
    const float* p = src + (size_t)row * NH + lane * 8;
    float4 v0 = *(const float4*)p;
    float4 v1 = *(const float4*)(p + 4);
    double s = (double)v0.x * v0.x + (double)v0.y * v0.y
             + (double)v0.z * v0.z + (double)v0.w * v0.w
             + (double)v1.x * v1.x + (double)v1.y * v1.y
             + (double)v1.z * v1.z + (double)v1.w * v1.w;
    uint4 pk;
    pk.x = pack_bf16_trunc(v0.x, v0.y);
    pk.y = pack_bf16_trunc(v0.z, v0.w);
    pk.z = pack_bf16_trunc(v1.x, v1.y);
    pk.w = pack_bf16_trunc(v1.z, v1.w);
    *(uint4*)(dst_bf + (size_t)row * NH + lane * 8) = pk;
    #pragma unroll
    for (int off = 32; off > 0; off >>= 1) s += __shfl_down(s, off, 64);
    if (lane == 0) inv_out[row] = 1.0 / sqrt(s);
}

// ---------------------------------------------------------------------------
// K1: ref_y fp32 -> fp16 (halves gather traffic; quant err ~1e-5 in output).
// ---------------------------------------------------------------------------
__global__ __launch_bounds__(256) void conv_ry_kernel(const float* __restrict__ ry,
                                                      __half* __restrict__ ryh)
{
    const int wave = threadIdx.x >> 6;
    const int lane = threadIdx.x & 63;
    const int row  = blockIdx.x * 4 + wave;
    float4 v = *(const float4*)(ry + (size_t)row * NO + lane * 4);
    __half2 h01 = __floats2half2_rn(v.x, v.y);
    __half2 h23 = __floats2half2_rn(v.z, v.w);
    uint2 pk;
    pk.x = __builtin_bit_cast(uint32_t, h01);
    pk.y = __builtin_bit_cast(uint32_t, h23);
    *(uint2*)(ryh + (size_t)row * NO + lane * 4) = pk;
}

// ---------------------------------------------------------------------------
// K2: sim = (x . rx^T)*xinv*rinv, bf16 MFMA, fp16 store.
// 128x128 tile, 4 waves (2x2 of 64x64), K=64 per LDS tile.
// (unchanged this round — no counter evidence against it yet)
// ---------------------------------------------------------------------------
__global__ __launch_bounds__(256) void gemm_kernel(const ushort* __restrict__ xbf,
                                                   const ushort* __restrict__ rxbf,
                                                   const double* __restrict__ xinv,
                                                   const double* __restrict__ rinv,
                                                   __half* __restrict__ sim)
{
    __shared__ ushort a_lds[128 * 64];
    __shared__ ushort b_lds[128 * 64];
    const int bid = blockIdx.x;
    const int nt  = (bid & 7) + 8 * (bid >> 6);
    const int mt  = (bid >> 3) & 7;
    if (nt >= (NR + 127) / 128) return;
    const int m0 = mt * 128;
    const int r0 = nt * 128;

    const int tid  = threadIdx.x;
    const int lane = tid & 63;
    const int wave = tid >> 6;
    const int wq = (wave >> 1) * 64;
    const int wr = (wave & 1) * 64;

    f32x4 acc[4][4];
    #pragma unroll
    for (int i = 0; i < 4; ++i)
        #pragma unroll
        for (int j = 0; j < 4; ++j)
            #pragma unroll
            for (int r = 0; r < 4; ++r) acc[i][j][r] = 0.0f;

    const int srow  = lane >> 3;              // 0..7 within instruction
    const int chunk = (lane & 7) ^ (srow & 7);// XOR-swizzled source chunk

    for (int kt = 0; kt < NH; kt += 64) {
        #pragma unroll
        for (int ii = 0; ii < 4; ++ii) {
            const int inst = wave * 4 + ii;       // 0..15, wave-uniform
            const int row  = inst * 8 + srow;     // 0..127
            const ushort* ga = xbf + (size_t)(m0 + row) * NH + kt + chunk * 8;
            __builtin_amdgcn_global_load_lds((glb_void*)ga,
                (lds_void*)(a_lds + inst * 512), 16, 0, 0);
            int rr = r0 + row; if (rr > NR - 1) rr = NR - 1;   // clamp: dup rows, discarded in epilogue
            const ushort* gb = rxbf + (size_t)rr * NH + kt + chunk * 8;
            __builtin_amdgcn_global_load_lds((glb_void*)gb,
                (lds_void*)(b_lds + inst * 512), 16, 0, 0);
        }
        __syncthreads();
        #pragma unroll
        for (int kc = 0; kc < 2; ++kc) {
            const int c  = kc * 4 + (lane >> 4);
            const int px = (c ^ (lane & 7)) * 8;
            bf16x8 af[4], bfr[4];
            #pragma unroll
            for (int i = 0; i < 4; ++i)
                af[i] = *(const bf16x8*)&a_lds[(wq + i * 16 + (lane & 15)) * 64 + px];
            #pragma unroll
            for (int j = 0; j < 4; ++j)
                bfr[j] = *(const bf16x8*)&b_lds[(wr + j * 16 + (lane & 15)) * 64 + px];
            #pragma unroll
            for (int i = 0; i < 4; ++i)
                #pragma unroll
                for (int j = 0; j < 4; ++j)
                    acc[i][j] = __builtin_amdgcn_mfma_f32_16x16x32_bf16(af[i], bfr[j], acc[i][j], 0, 0, 0);
        }
        __syncthreads();
    }

    // epilogue: C/D layout col=lane&15 (n), row=(lane>>4)*4+reg (m)
    float xi[4][4];
    #pragma unroll
    for (int i = 0; i < 4; ++i) {
        int mb = m0 + wq + i * 16 + (lane >> 4) * 4;
        #pragma unroll
        for (int r = 0; r < 4; ++r) xi[i][r] = (float)xinv[mb + r];
    }
    #pragma unroll
    for (int j = 0; j < 4; ++j) {
        int nn = r0 + wr + j * 16 + (lane & 15);
        if (nn < NR) {
            float rv = (float)rinv[nn];
            #pragma unroll
            for (int i = 0; i < 4; ++i) {
                int mb = m0 + wq + i * 16 + (lane >> 4) * 4;
                #pragma unroll
                for (int r = 0; r < 4; ++r)
                    sim[(size_t)(mb + r) * NR + nn] = __float2half(acc[i][j][r] * xi[i][r] * rv);
            }
        }
    }
}

// ---------------------------------------------------------------------------
// K3: fused histogram + threshold + collect (one block per query row).
// (unchanged this round)
// ---------------------------------------------------------------------------
__global__ __launch_bounds__(256) void hist_collect_kernel(const __half* __restrict__ sim,
                                                           uint32_t* __restrict__ def_cnt,
                                                           uint32_t* __restrict__ cand_cnt,
                                                           float* __restrict__ def_val,
                                                           uint32_t* __restrict__ def_idx,
                                                           uint32_t* __restrict__ cand_idx)
{
    __shared__ uint32_t h[NBINS];     // 16 KB
    __shared__ uint32_t ps[256];
    __shared__ float s_thi, s_tlo;
    __shared__ uint32_t s_dc, s_cc;
    const int n = blockIdx.x, tid = threadIdx.x;
    for (int b = tid; b < NBINS; b += 256) h[b] = 0u;
    __syncthreads();
    const uint4* row8 = (const uint4*)(sim + (size_t)n * NR);
    for (int i8 = tid; i8 < NR / 8; i8 += 256) {
        uint4 v = row8[i8];
        uint32_t ws[4] = {v.x, v.y, v.z, v.w};
        #pragma unroll
        for (int c = 0; c < 4; ++c) {
            float2 f = __half22float2(__builtin_bit_cast(__half2, ws[c]));
            int b0 = (int)((f.x + 1.0f) * 2048.0f); b0 = min(max(b0, 0), NBINS - 1); atomicAdd(&h[b0], 1u);
            int b1 = (int)((f.y + 1.0f) * 2048.0f); b1 = min(max(b1, 0), NBINS - 1); atomicAdd(&h[b1], 1u);
        }
    }
    __syncthreads();
    uint32_t cs = 0;
    #pragma unroll 4
    for (int b = 0; b < 16; ++b) cs += h[tid * 16 + b];
    ps[tid] = cs;
    __syncthreads();
    if (tid == 0) {
        uint32_t acc = 0; int tc = 0;
        for (int t2 = 255; t2 >= 0; --t2) {
            if (acc + ps[t2] >= (uint32_t)NK) { tc = t2; break; }
            acc += ps[t2];
        }
        int bstar = tc * 16;
        for (int b = tc * 16 + 15; b >= tc * 16; --b) {
            acc += h[b];
            if (acc >= (uint32_t)NK) { bstar = b; break; }
        }
        s_thi = (float)(bstar + 1) * (1.0f / 2048.0f) - 1.0f + DELTA;
        s_tlo = (float)bstar * (1.0f / 2048.0f) - 1.0f - DELTA;
        s_dc = 0u; s_cc = 0u;
    }
    __syncthreads();
    const float thi = s_thi, tlo = s_tlo;
    for (int i8 = tid; i8 < NR / 8; i8 += 256) {
        uint4 v = row8[i8];
        uint32_t ws[4] = {v.x, v.y, v.z, v.w};
        const int base = i8 * 8;
        #pragma unroll
        for (int c = 0; c < 4; ++c) {
            float2 f = __half22float2(__builtin_bit_cast(__half2, ws[c]));
            float sv[2] = {f.x, f.y};
            #pragma unroll
            for (int d = 0; d < 2; ++d) {
                float s = sv[d];
                if (s > thi) {
                    uint32_t p = atomicAdd(&s_dc, 1u);
                    if (p < DEF_CAP) {
                        def_val[(size_t)n * DEF_CAP + p] = s;
                        def_idx[(size_t)n * DEF_CAP + p] = (uint32_t)(base + c * 2 + d);
                    }
                } else if (s >= tlo) {
                    uint32_t p = atomicAdd(&s_cc, 1u);
                    if (p < CND_CAP) cand_idx[(size_t)n * CND_CAP + p] = (uint32_t)(base + c * 2 + d);
                }
            }
        }
    }
    __syncthreads();
    if (tid == 0) {
        def_cnt[n]  = s_dc < DEF_CAP ? s_dc : DEF_CAP;
        cand_cnt[n] = s_cc < CND_CAP ? s_cc : CND_CAP;
    }
}

// ---------------------------------------------------------------------------
// K4: exact fp64 candidate resolution + softmax + fp16 weighted gather.
// RESTRUCTURED for memory-level parallelism (was latency-bound: 22% HBM,
// 24% VALU, 87% occupancy):
//  - cand indices prefetched to LDS; x-row hoisted to registers (16 floats/lane)
//  - candidate dots at HALF-WAVE granularity, 2 candidates in flight per
//    half-wave: 64 concurrent candidates/block, 8x float4 loads in flight
//    (was: 1 candidate/wave, dependent 4B scalar load chain)
//  - gather: 32-way k-split, uint4 (16B) loads, 2 rows in flight
//  - softmax: shuffle reductions (5 barriers total, was ~22)
// fp64 math & selection semantics unchanged.
// ---------------------------------------------------------------------------
__global__ __launch_bounds__(1024) void final_kernel(const float* __restrict__ x,
                                                     const float* __restrict__ rx,
                                                     const __half* __restrict__ ryh,
                                                     const double* __restrict__ xinv,
                                                     const double* __restrict__ rinv,
                                                     const uint32_t* __restrict__ def_cnt,
                                                     const uint32_t* __restrict__ cand_cnt,
                                                     const float* __restrict__ def_val,
                                                     const uint32_t* __restrict__ def_idx,
                                                     const uint32_t* __restrict__ cand_idx,
                                                     float* __restrict__ out)
{
    const int n = blockIdx.x, tid = threadIdx.x;
    const int lane = tid & 63, wave = tid >> 6;
    const int hl = lane & 31;           // half-wave lane
    const int slot = tid >> 5;          // 0..31 half-wave id in block
    __shared__ double   cvd[CND_CAP];
    __shared__ uint32_t ci[CND_CAP];
    __shared__ float    sel_w[DEF_CAP];
    __shared__ uint32_t sel_idx[DEF_CAP];
    __shared__ float    red[16];
    __shared__ float    s_r[32][264];   // +8 pad keeps float4 alignment, spreads banks
    __shared__ uint32_t s_sel;

    const int ca = (int)def_cnt[n];
    const int cb = (int)cand_cnt[n];
    int t = NK - ca; if (t > cb) t = cb; if (t < 0) t = 0;

    for (int j = tid; j < ca; j += 1024) {
        sel_w[j]   = def_val[(size_t)n * DEF_CAP + j];
        sel_idx[j] = def_idx[(size_t)n * DEF_CAP + j];
    }
    for (int j = tid; j < cb; j += 1024)
        ci[j] = cand_idx[(size_t)n * CND_CAP + j];
    if (tid == 0) s_sel = 0u;
    __syncthreads();

    // ---- candidate fp64 dots: half-wave per candidate, 2 in flight ----
    const float* xr = x + (size_t)n * NH;
    float4 xv[4];
    #pragma unroll
    for (int i = 0; i < 4; ++i) xv[i] = *(const float4*)(xr + hl * 4 + i * 128);
    const double xin = xinv[n];

    for (int j = slot; j < cb; j += 64) {
        const int j2 = j + 32;
        const bool has2 = (j2 < cb);
        const float* r1 = rx + (size_t)ci[j] * NH;
        const float* r2 = rx + (size_t)ci[has2 ? j2 : j] * NH;
        float4 ra[4], rb[4];
        #pragma unroll
        for (int i = 0; i < 4; ++i) ra[i] = *(const float4*)(r1 + hl * 4 + i * 128);
        #pragma unroll
        for (int i = 0; i < 4; ++i) rb[i] = *(const float4*)(r2 + hl * 4 + i * 128);
        double sA = 0.0, sB = 0.0;
        #pragma unroll
        for (int i = 0; i < 4; ++i) {
            sA += (double)xv[i].x * ra[i].x + (double)xv[i].y * ra[i].y
                + (double)xv[i].z * ra[i].z + (double)xv[i].w * ra[i].w;
            sB += (double)xv[i].x * rb[i].x + (double)xv[i].y * rb[i].y
                + (double)xv[i].z * rb[i].z + (double)xv[i].w * rb[i].w;
        }
        #pragma unroll
        for (int off = 16; off > 0; off >>= 1) {
            sA += __shfl_down(sA, off, 64);
            sB += __shfl_down(sB, off, 64);
        }
        if (hl == 0) {
            cvd[j] = (sA * xin) * rinv[ci[j]];
            if (has2) cvd[j2] = (sB * xin) * rinv[ci[j2]];
        }
    }
    __syncthreads();

    // ---- exact rank select (val desc, idx asc) matching top_k semantics ----
    if (tid < cb) {
        double vj = cvd[tid]; uint32_t ij = ci[tid];
        int rank = 0;
        for (int i = 0; i < cb; ++i) {
            double vi = cvd[i];
            rank += (vi > vj) || (vi == vj && ci[i] < ij);
        }
        if (rank < t) {
            uint32_t p = atomicAdd(&s_sel, 1u);
            sel_w[ca + p]   = (float)vj;
            sel_idx[ca + p] = ij;
        }
    }
    __syncthreads();
    const int M = ca + t;

    // ---- softmax: wave shuffle reductions ----
    float lm = -3.0e38f;
    for (int k = tid; k < M; k += 1024) lm = fmaxf(lm, sel_w[k]);
    #pragma unroll
    for (int off = 32; off > 0; off >>= 1) lm = fmaxf(lm, __shfl_xor(lm, off, 64));
    if (lane == 0) red[wave] = lm;
    __syncthreads();
    float mx = red[0];
    #pragma unroll
    for (int w2 = 1; w2 < 16; ++w2) mx = fmaxf(mx, red[w2]);
    __syncthreads();    // protect red reuse

    float ls = 0.f;
    for (int k = tid; k < M; k += 1024) {
        float w = expf(sel_w[k] - mx);
        sel_w[k] = w;
        ls += w;
    }
    #pragma unroll
    for (int off = 32; off > 0; off >>= 1) ls += __shfl_xor(ls, off, 64);
    if (lane == 0) red[wave] = ls;
    __syncthreads();    // also makes sel_w[] writes visible for gather
    float wsum = red[0];
    #pragma unroll
    for (int w2 = 1; w2 < 16; ++w2) wsum += red[w2];

    // ---- gather: 32-way k-split, half-wave covers 8 cols (16B), 2 rows in flight
    float acc[8];
    #pragma unroll
    for (int c = 0; c < 8; ++c) acc[c] = 0.f;
    for (int k = slot; k < M; k += 64) {
        const int k2 = k + 32;
        const bool has2 = (k2 < M);
        const uint4 v1 = *(const uint4*)(ryh + (size_t)sel_idx[k] * NO + hl * 8);
        const uint4 v2 = *(const uint4*)(ryh + (size_t)sel_idx[has2 ? k2 : k] * NO + hl * 8);
        const float w1 = sel_w[k];
        const float w2 = has2 ? sel_w[k2] : 0.f;
        float2 f;
        f = __half22float2(__builtin_bit_cast(__half2, v1.x)); acc[0] = fmaf(w1, f.x, acc[0]); acc[1] = fmaf(w1, f.y, acc[1]);
        f = __half22float2(__builtin_bit_cast(__half2, v1.y)); acc[2] = fmaf(w1, f.x, acc[2]); acc[3] = fmaf(w1, f.y, acc[3]);
        f = __half22float2(__builtin_bit_cast(__half2, v1.z)); acc[4] = fmaf(w1, f.x, acc[4]); acc[5] = fmaf(w1, f.y, acc[5]);
        f = __half22float2(__builtin_bit_cast(__half2, v1.w)); acc[6] = fmaf(w1, f.x, acc[6]); acc[7] = fmaf(w1, f.y, acc[7]);
        f = __half22float2(__builtin_bit_cast(__half2, v2.x)); acc[0] = fmaf(w2, f.x, acc[0]); acc[1] = fmaf(w2, f.y, acc[1]);
        f = __half22float2(__builtin_bit_cast(__half2, v2.y)); acc[2] = fmaf(w2, f.x, acc[2]); acc[3] = fmaf(w2, f.y, acc[3]);
        f = __half22float2(__builtin_bit_cast(__half2, v2.z)); acc[4] = fmaf(w2, f.x, acc[4]); acc[5] = fmaf(w2, f.y, acc[5]);
        f = __half22float2(__builtin_bit_cast(__half2, v2.w)); acc[6] = fmaf(w2, f.x, acc[6]); acc[7] = fmaf(w2, f.y, acc[7]);
    }
    *(float4*)&s_r[slot][hl * 8 + 0] = make_float4(acc[0], acc[1], acc[2], acc[3]);
    *(float4*)&s_r[slot][hl * 8 + 4] = make_float4(acc[4], acc[5], acc[6], acc[7]);
    __syncthreads();
    if (tid < 256) {
        float s = 0.f;
        #pragma unroll
        for (int p = 0; p < 32; ++p) s += s_r[p][tid];
        out[(size_t)n * NO + tid] = s / wsum;
    }
}

// ---------------------------------------------------------------------------
// Workspace layout (bytes), total 371,799,296 (< round-1-proven 423,007,488):
//   simh     :           0   f16 [1024][100000]    204,800,000
//   rxbf     : 204,800,000   bf16 [100000][512]    102,400,000
//   ryh      : 307,200,000   f16 [100000][256]      51,200,000
//   xbf      : 358,400,000   bf16 [1024][512]        1,048,576
//   rinv     : 359,448,576   f64 x 100000              800,000
//   xinv     : 360,248,576   f64 x 1024                  8,192
//   def_cnt  : 360,256,768   u32 x 1024                  4,096
//   cand_cnt : 360,260,864   u32 x 1024                  4,096
//   def_val  : 360,264,960   f32 [1024][1024]        4,194,304
//   def_idx  : 364,459,264   u32 [1024][1024]        4,194,304
//   cand_idx : 368,653,568   u32 [1024][768]         3,145,728
// ---------------------------------------------------------------------------
extern "C" void kernel_launch(void* const* d_in, const int* in_sizes, int n_in,
                              void* d_out, int out_size, void* d_ws, size_t ws_size,
                              hipStream_t stream)
{
    const float* x  = (const float*)d_in[0];
    const float* rx = (const float*)d_in[1];
    const float* ry = (const float*)d_in[2];
    float* out = (float*)d_out;

    char* ws = (char*)d_ws;
    __half*   simh     = (__half*)(ws);
    ushort*   rxbf     = (ushort*)(ws + 204800000ull);
    __half*   ryh      = (__half*)(ws + 307200000ull);
    ushort*   xbf      = (ushort*)(ws + 358400000ull);
    double*   rinv     = (double*)(ws + 359448576ull);
    double*   xinv     = (double*)(ws + 360248576ull);
    uint32_t* def_cnt  = (uint32_t*)(ws + 360256768ull);
    uint32_t* cand_cnt = (uint32_t*)(ws + 360260864ull);
    float*    def_val  = (float*)(ws + 360264960ull);
    uint32_t* def_idx  = (uint32_t*)(ws + 364459264ull);
    uint32_t* cand_idx = (uint32_t*)(ws + 368653568ull);

    conv_norm_kernel<<<NQ / 4, 256, 0, stream>>>(x, NQ, xbf, xinv);
    conv_norm_kernel<<<NR / 4, 256, 0, stream>>>(rx, NR, rxbf, rinv);
    conv_ry_kernel<<<NR / 4, 256, 0, stream>>>(ry, ryh);
    gemm_kernel<<<6272, 256, 0, stream>>>(xbf, rxbf, xinv, rinv, simh);
    hist_collect_kernel<<<NQ, 256, 0, stream>>>(simh, def_cnt, cand_cnt,
                                                def_val, def_idx, cand_idx);
    final_kernel<<<NQ, 1024, 0, stream>>>(x, rx, ryh, xinv, rinv, def_cnt, cand_cnt,
                                          def_val, def_idx, cand_idx, out);
}